// Round 1
// baseline (809.707 us; speedup 1.0000x reference)
//
#include <hip/hip_runtime.h>
#include <cstdint>
#include <cstddef>

#define D_MODEL 1024
#define SEQ 8192

typedef __bf16  bf16x8 __attribute__((ext_vector_type(8)));
typedef short   short8 __attribute__((ext_vector_type(8)));
typedef float   f32x4  __attribute__((ext_vector_type(4)));
typedef unsigned short ushort_t;

__device__ __forceinline__ ushort_t f2bf(float f) {
  uint32_t u = __builtin_bit_cast(uint32_t, f);
  u += 0x7FFFu + ((u >> 16) & 1u);          // round-to-nearest-even
  return (ushort_t)(u >> 16);
}
__device__ __forceinline__ float bf2f(ushort_t h) {
  return __builtin_bit_cast(float, (uint32_t)h << 16);
}
// async global->LDS, 16B per lane. LDS dest is wave-uniform base + lane*16.
__device__ __forceinline__ void gll16(const void* g, void* l) {
  __builtin_amdgcn_global_load_lds(
      (const __attribute__((address_space(1))) void*)g,
      (__attribute__((address_space(3))) void*)l, 16, 0, 0);
}

// ---------------- fp32 -> bf16 conversion of x ----------------
__global__ void k_convert_x(const float* __restrict__ x, ushort_t* __restrict__ xb, int n) {
  int i = (blockIdx.x * 256 + threadIdx.x) * 8;
  if (i >= n) return;
  float4 v0 = *(const float4*)(x + i);
  float4 v1 = *(const float4*)(x + i + 4);
  ushort_t o[8] = { f2bf(v0.x), f2bf(v0.y), f2bf(v0.z), f2bf(v0.w),
                    f2bf(v1.x), f2bf(v1.y), f2bf(v1.z), f2bf(v1.w) };
  *(short8*)(xb + i) = *(const short8*)o;
}

// ---------------- W (k,n) fp32 -> Wt (n,k) bf16 ----------------
__global__ void k_transpose_w(const float* W0, const float* W1, const float* W2, const float* W3,
                              ushort_t* T0, ushort_t* T1, ushort_t* T2, ushort_t* T3) {
  const float* src; ushort_t* dst;
  switch (blockIdx.z) {
    case 0: src = W0; dst = T0; break;
    case 1: src = W1; dst = T1; break;
    case 2: src = W2; dst = T2; break;
    default: src = W3; dst = T3; break;
  }
  __shared__ float tile[64][65];
  int tx = threadIdx.x;
  int c = tx & 63, r0 = tx >> 6;
  int bx = blockIdx.x * 64, by = blockIdx.y * 64;
  #pragma unroll
  for (int i = 0; i < 16; i++) {
    int r = i * 4 + r0;
    tile[r][c] = src[(size_t)(by + r) * D_MODEL + bx + c];
  }
  __syncthreads();
  #pragma unroll
  for (int i = 0; i < 16; i++) {
    int r = i * 4 + r0;
    dst[(size_t)(bx + r) * D_MODEL + by + c] = f2bf(tile[c][r]);
  }
}

// ---------------- m97-style bf16 GEMM: C = A(M,K) * Bt(N,K)^T + bias ----------------
// MODE 0: bf16 out + feature map (elu+1); MODE 1: bf16 out; MODE 2: fp32 out
template<int MODE>
__global__ __launch_bounds__(256) void k_gemm(const ushort_t* __restrict__ A,
                                              const ushort_t* __restrict__ Bt,
                                              const float* __restrict__ bias,
                                              ushort_t* __restrict__ outb,
                                              float* __restrict__ outf) {
  __shared__ __align__(16) ushort_t As[128 * 32];
  __shared__ __align__(16) ushort_t Bs[128 * 32];
  const int tid = threadIdx.x;
  const int ln = tid & 63;
  const int w = tid >> 6;
  const int wr = (w >> 1) * 64, wc = (w & 1) * 64;
  const int m0 = blockIdx.x * 128;
  const int n0 = blockIdx.y * 128;

  const int lr = tid >> 2;
  const int kg = (tid & 3) * 8;
  const ushort_t* gA0 = A + (size_t)(m0 + lr) * D_MODEL + kg;
  const ushort_t* gA1 = gA0 + (size_t)64 * D_MODEL;
  const ushort_t* gB0 = Bt + (size_t)(n0 + lr) * D_MODEL + kg;
  const ushort_t* gB1 = gB0 + (size_t)64 * D_MODEL;

  const int wb = __builtin_amdgcn_readfirstlane(w);
  ushort_t* lA0 = As + wb * 512;
  ushort_t* lA1 = As + 2048 + wb * 512;
  ushort_t* lB0 = Bs + wb * 512;
  ushort_t* lB1 = Bs + 2048 + wb * 512;

  f32x4 acc[4][4];
  #pragma unroll
  for (int i = 0; i < 4; i++)
    #pragma unroll
    for (int j = 0; j < 4; j++) acc[i][j] = (f32x4){0.f, 0.f, 0.f, 0.f};

  const int ar = ln & 15;
  const int aq = (ln >> 4) * 8;

  for (int kt = 0; kt < D_MODEL / 32; kt++) {
    gll16(gA0, lA0); gll16(gA1, lA1);
    gll16(gB0, lB0); gll16(gB1, lB1);
    gA0 += 32; gA1 += 32; gB0 += 32; gB1 += 32;
    __syncthreads();   // drains vmcnt(0) -> LDS tiles ready
    bf16x8 a[4], b[4];
    #pragma unroll
    for (int i = 0; i < 4; i++) a[i] = *(const bf16x8*)&As[(wr + i * 16 + ar) * 32 + aq];
    #pragma unroll
    for (int j = 0; j < 4; j++) b[j] = *(const bf16x8*)&Bs[(wc + j * 16 + ar) * 32 + aq];
    #pragma unroll
    for (int i = 0; i < 4; i++)
      #pragma unroll
      for (int j = 0; j < 4; j++)
        acc[i][j] = __builtin_amdgcn_mfma_f32_16x16x32_bf16(a[i], b[j], acc[i][j], 0, 0, 0);
    __syncthreads();   // all reads done before next overwrite
  }

  // epilogue: C/D layout col=lane&15, row=(lane>>4)*4+reg  [m89-verified]
  const int colb = ln & 15;
  const int rowb = (ln >> 4) * 4;
  #pragma unroll
  for (int j = 0; j < 4; j++) {
    int col = n0 + wc + j * 16 + colb;
    float bv = bias[col];
    #pragma unroll
    for (int i = 0; i < 4; i++) {
      int row = m0 + wr + i * 16 + rowb;
      #pragma unroll
      for (int r = 0; r < 4; r++) {
        float v = acc[i][j][r] + bv;
        if (MODE == 0) v = (v > 0.f) ? v + 1.f : __expf(v);  // elu(v)+1
        if (MODE == 2) outf[(size_t)(row + r) * D_MODEL + col] = v;
        else           outb[(size_t)(row + r) * D_MODEL + col] = f2bf(v);
      }
    }
  }
}

// ---------------- kv partial: per (b,h,chunk,wave) 64x64 outer-product sum + ksum ----------------
// grid (8 chunks, B*16), block 256 (4 waves, each 256 rows). Partials -> ws (no atomics).
__global__ __launch_bounds__(256) void k_kv_partial(const ushort_t* __restrict__ kmat,
                                                    const ushort_t* __restrict__ vmat,
                                                    float* __restrict__ part) {
  __shared__ __align__(16) ushort_t sbuf[4][2][2][512];  // [wave][parity][k/v][8rows*64]
  const int tid = threadIdx.x, ln = tid & 63, w = tid >> 6;
  const int wb = __builtin_amdgcn_readfirstlane(w);
  const int bh = blockIdx.y, chunk = blockIdx.x;
  const int b = bh >> 4, h = bh & 15;
  const size_t cbase = ((size_t)b * SEQ + chunk * 1024 + w * 256) * D_MODEL + h * 64;
  const ushort_t* gk = kmat + cbase + (size_t)(ln >> 3) * D_MODEL + (ln & 7) * 8;
  const ushort_t* gv = vmat + cbase + (size_t)(ln >> 3) * D_MODEL + (ln & 7) * 8;

  float acc[8][8];
  float ksum[8];
  #pragma unroll
  for (int i = 0; i < 8; i++) { ksum[i] = 0.f;
    #pragma unroll
    for (int j = 0; j < 8; j++) acc[i][j] = 0.f; }

  const int r8 = (ln >> 3) * 8, c8 = (ln & 7) * 8;
  gll16(gk, &sbuf[wb][0][0][0]);
  gll16(gv, &sbuf[wb][0][1][0]);
  gk += 8 * D_MODEL; gv += 8 * D_MODEL;

  for (int bt = 0; bt < 32; bt++) {
    const int p = bt & 1;
    if (bt < 31) {
      gll16(gk, &sbuf[wb][p ^ 1][0][0]);
      gll16(gv, &sbuf[wb][p ^ 1][1][0]);
      gk += 8 * D_MODEL; gv += 8 * D_MODEL;
      __builtin_amdgcn_s_waitcnt(0x0F72);  // vmcnt(2): current batch landed
    } else {
      __builtin_amdgcn_s_waitcnt(0x0F70);  // vmcnt(0)
    }
    #pragma unroll
    for (int s = 0; s < 8; s++) {
      short8 kk = *(const short8*)&sbuf[wb][p][0][s * 64 + r8];
      short8 vv = *(const short8*)&sbuf[wb][p][1][s * 64 + c8];
      float ka[8], va[8];
      #pragma unroll
      for (int i = 0; i < 8; i++) {
        ka[i] = __builtin_bit_cast(float, (uint32_t)(ushort_t)kk[i] << 16);
        va[i] = __builtin_bit_cast(float, (uint32_t)(ushort_t)vv[i] << 16);
      }
      #pragma unroll
      for (int i = 0; i < 8; i++) {
        ksum[i] += ka[i];
        #pragma unroll
        for (int j = 0; j < 8; j++) acc[i][j] += ka[i] * va[j];
      }
    }
  }
  float* p0 = part + ((size_t)bh * 32 + chunk * 4 + w) * 4160;
  #pragma unroll
  for (int i = 0; i < 8; i++)
    #pragma unroll
    for (int j = 0; j < 8; j++) p0[(r8 + i) * 64 + c8 + j] = acc[i][j];
  if ((ln & 7) == 0) {
    #pragma unroll
    for (int i = 0; i < 8; i++) p0[4096 + r8 + i] = ksum[i];
  }
}

// ---------------- reduce partials -> kvT bf16 [bh][65][64] (row m holds kv[.][m]; row 64 = ksum) ----------------
__global__ void k_kv_reduce(const float* __restrict__ part, ushort_t* __restrict__ kvt) {
  const int bh = blockIdx.x, tid = threadIdx.x;
  const float* p0 = part + (size_t)bh * 32 * 4160;
  for (int idx = tid; idx < 4160; idx += 256) {
    float s = 0.f;
    #pragma unroll 4
    for (int c = 0; c < 32; c++) s += p0[(size_t)c * 4160 + idx];
    ushort_t bf = f2bf(s);
    if (idx < 4096) { int d = idx >> 6, m = idx & 63; kvt[(size_t)bh * 4160 + m * 64 + d] = bf; }
    else            { kvt[(size_t)bh * 4160 + 4096 + (idx - 4096)] = bf; }
  }
}

// ---------------- attn: out = (q @ kv) / max(q . ksum, eps), bf16 out ----------------
// grid (SEQ/256, B*16), block 256; wave handles 64 rows; norm via extra MFMA with ksum-broadcast B-frag.
__global__ __launch_bounds__(256) void k_attn(const ushort_t* __restrict__ qmat,
                                              const ushort_t* __restrict__ kvt,
                                              ushort_t* __restrict__ attn) {
  __shared__ __align__(16) ushort_t kvs[65 * 80];     // kvT rows stride 80
  __shared__ __align__(16) ushort_t qs[4][64 * 80];   // per-wave q tile, stride 80
  const int tid = threadIdx.x, ln = tid & 63, w = tid >> 6;
  const int bh = blockIdx.y, b = bh >> 4, h = bh & 15;

  for (int idx = tid; idx < 4160; idx += 256) {
    int m = idx >> 6, d = idx & 63;
    kvs[m * 80 + d] = kvt[(size_t)bh * 4160 + idx];
  }
  const size_t s0 = (size_t)b * SEQ + blockIdx.x * 256 + w * 64;
  #pragma unroll
  for (int c = 0; c < 8; c++) {
    int f = c * 64 + ln;
    int row = f >> 3, dg = (f & 7) * 8;
    short8 t = *(const short8*)&qmat[(s0 + row) * D_MODEL + h * 64 + dg];
    *(short8*)&qs[w][row * 80 + dg] = t;
  }
  __syncthreads();

  const int ar = ln & 15, aq = (ln >> 4) * 8;
  f32x4 acc[4][4], nacc[4];
  #pragma unroll
  for (int i = 0; i < 4; i++) { nacc[i] = (f32x4){0.f, 0.f, 0.f, 0.f};
    #pragma unroll
    for (int j = 0; j < 4; j++) acc[i][j] = (f32x4){0.f, 0.f, 0.f, 0.f}; }

  #pragma unroll
  for (int kk = 0; kk < 2; kk++) {
    const int ko = kk * 32 + aq;
    bf16x8 a[4], bb[4], bn;
    #pragma unroll
    for (int i = 0; i < 4; i++) a[i] = *(const bf16x8*)&qs[w][(i * 16 + ar) * 80 + ko];
    #pragma unroll
    for (int j = 0; j < 4; j++) bb[j] = *(const bf16x8*)&kvs[(j * 16 + ar) * 80 + ko];
    bn = *(const bf16x8*)&kvs[64 * 80 + ko];
    #pragma unroll
    for (int i = 0; i < 4; i++) {
      #pragma unroll
      for (int j = 0; j < 4; j++)
        acc[i][j] = __builtin_amdgcn_mfma_f32_16x16x32_bf16(a[i], bb[j], acc[i][j], 0, 0, 0);
      nacc[i] = __builtin_amdgcn_mfma_f32_16x16x32_bf16(a[i], bn, nacc[i], 0, 0, 0);
    }
  }

  const int colb = ln & 15, rowb = (ln >> 4) * 4;
  #pragma unroll
  for (int i = 0; i < 4; i++) {
    #pragma unroll
    for (int r = 0; r < 4; r++) {
      const int row = i * 16 + rowb + r;
      float nm = fmaxf(nacc[i][r], 1e-6f);
      float inv = 1.0f / nm;
      const size_t grow = s0 + row;
      #pragma unroll
      for (int j = 0; j < 4; j++) {
        float v = acc[i][j][r] * inv;
        attn[grow * D_MODEL + h * 64 + j * 16 + colb] = f2bf(v);
      }
    }
  }
}

extern "C" void kernel_launch(void* const* d_in, const int* in_sizes, int n_in,
                              void* d_out, int out_size, void* d_ws, size_t ws_size,
                              hipStream_t stream) {
  const float* x  = (const float*)d_in[0];
  const float* Wq = (const float*)d_in[1];
  const float* bq = (const float*)d_in[2];
  const float* Wk = (const float*)d_in[3];
  const float* bk = (const float*)d_in[4];
  const float* Wv = (const float*)d_in[5];
  const float* bv = (const float*)d_in[6];
  const float* Wo = (const float*)d_in[7];
  const float* bo = (const float*)d_in[8];
  float* out = (float*)d_out;

  const int M = in_sizes[0] / D_MODEL;       // 32768
  const int B = M / SEQ;                     // 4
  const int BH = B * 16;                     // 64

  char* ws = (char*)d_ws;
  size_t off = 0;
  auto alloc = [&](size_t bytes) { char* p = ws + off; off += (bytes + 255) & ~(size_t)255; return p; };
  const size_t mb = (size_t)M * D_MODEL * 2;               // 64 MB per bf16 matrix
  ushort_t* xb    = (ushort_t*)alloc(mb);
  ushort_t* qb    = (ushort_t*)alloc(mb);
  ushort_t* kb    = (ushort_t*)alloc(mb);
  ushort_t* vb    = (ushort_t*)alloc(mb);
  ushort_t* attnb = (ushort_t*)alloc(mb);
  ushort_t* wqt   = (ushort_t*)alloc((size_t)D_MODEL * D_MODEL * 2);
  ushort_t* wkt   = (ushort_t*)alloc((size_t)D_MODEL * D_MODEL * 2);
  ushort_t* wvt   = (ushort_t*)alloc((size_t)D_MODEL * D_MODEL * 2);
  ushort_t* wot   = (ushort_t*)alloc((size_t)D_MODEL * D_MODEL * 2);
  ushort_t* kvt   = (ushort_t*)alloc((size_t)BH * 4160 * 2);
  float*    part  = (float*)   alloc((size_t)BH * 32 * 4160 * 4);
  (void)ws_size; (void)n_in; (void)out_size;

  const int n = M * D_MODEL;
  k_convert_x<<<n / (256 * 8), 256, 0, stream>>>(x, xb, n);
  k_transpose_w<<<dim3(16, 16, 4), 256, 0, stream>>>(Wq, Wk, Wv, Wo, wqt, wkt, wvt, wot);

  dim3 gg(M / 128, 8);
  k_gemm<0><<<gg, 256, 0, stream>>>(xb, wqt, bq, qb, nullptr);
  k_gemm<0><<<gg, 256, 0, stream>>>(xb, wkt, bk, kb, nullptr);
  k_gemm<1><<<gg, 256, 0, stream>>>(xb, wvt, bv, vb, nullptr);

  k_kv_partial<<<dim3(8, BH), 256, 0, stream>>>(kb, vb, part);
  k_kv_reduce<<<BH, 256, 0, stream>>>(part, kvt);
  k_attn<<<dim3(SEQ / 256, BH), 256, 0, stream>>>(qb, kvt, attnb);

  k_gemm<2><<<gg, 256, 0, stream>>>(attnb, wot, bo, nullptr, out);
}

// Round 2
// 751.939 us; speedup vs baseline: 1.0768x; 1.0768x over previous
//
#include <hip/hip_runtime.h>
#include <cstdint>
#include <cstddef>

#define D_MODEL 1024
#define SEQ 8192

typedef __bf16  bf16x8 __attribute__((ext_vector_type(8)));
typedef short   short8 __attribute__((ext_vector_type(8)));
typedef float   f32x4  __attribute__((ext_vector_type(4)));
typedef unsigned short ushort_t;

__device__ __forceinline__ ushort_t f2bf(float f) {
  uint32_t u = __builtin_bit_cast(uint32_t, f);
  u += 0x7FFFu + ((u >> 16) & 1u);          // round-to-nearest-even
  return (ushort_t)(u >> 16);
}
// async global->LDS, 16B per lane. LDS dest is wave-uniform base + lane*16.
__device__ __forceinline__ void gll16(const void* g, void* l) {
  __builtin_amdgcn_global_load_lds(
      (const __attribute__((address_space(1))) void*)g,
      (__attribute__((address_space(3))) void*)l, 16, 0, 0);
}

// ---------------- fp32 -> bf16 conversion of x ----------------
__global__ void k_convert_x(const float* __restrict__ x, ushort_t* __restrict__ xb, int n) {
  int i = (blockIdx.x * 256 + threadIdx.x) * 8;
  if (i >= n) return;
  float4 v0 = *(const float4*)(x + i);
  float4 v1 = *(const float4*)(x + i + 4);
  ushort_t o[8] = { f2bf(v0.x), f2bf(v0.y), f2bf(v0.z), f2bf(v0.w),
                    f2bf(v1.x), f2bf(v1.y), f2bf(v1.z), f2bf(v1.w) };
  *(short8*)(xb + i) = *(const short8*)o;
}

// ---------------- W (k,n) fp32 -> Wt (n,k) bf16; z<3 -> fused qkv buffer ----------------
__global__ void k_transpose_w(const float* W0, const float* W1, const float* W2, const float* W3,
                              ushort_t* Tqkv, ushort_t* To) {
  const float* src; ushort_t* dst;
  switch (blockIdx.z) {
    case 0: src = W0; dst = Tqkv; break;
    case 1: src = W1; dst = Tqkv + (size_t)1024 * 1024; break;
    case 2: src = W2; dst = Tqkv + (size_t)2048 * 1024; break;
    default: src = W3; dst = To; break;
  }
  __shared__ float tile[64][65];
  int tx = threadIdx.x;
  int c = tx & 63, r0 = tx >> 6;
  int bx = blockIdx.x * 64, by = blockIdx.y * 64;
  #pragma unroll
  for (int i = 0; i < 16; i++) {
    int r = i * 4 + r0;
    tile[r][c] = src[(size_t)(by + r) * D_MODEL + bx + c];
  }
  __syncthreads();
  #pragma unroll
  for (int i = 0; i < 16; i++) {
    int r = i * 4 + r0;
    dst[(size_t)(bx + r) * D_MODEL + by + c] = f2bf(tile[c][r]);
  }
}

// ---------------- m97-style bf16 GEMM: C = A(M,K) * Bt(N,K)^T + bias ----------------
// MODE 0: fused QKV (N=3072): region 0/1 -> elu+1 -> o0/o1; region 2 -> o2 (plain). bf16 out.
// MODE 2: fp32 out (+bias), single output.
// 1D grid, decoded N-fastest so consecutive blocks share the A-tile (L2 reuse).
template<int MODE, int NY>
__global__ __launch_bounds__(256) void k_gemm(const ushort_t* __restrict__ A,
                                              const ushort_t* __restrict__ Bt,
                                              const float* __restrict__ b0,
                                              const float* __restrict__ b1,
                                              const float* __restrict__ b2,
                                              ushort_t* __restrict__ o0,
                                              ushort_t* __restrict__ o1,
                                              ushort_t* __restrict__ o2,
                                              float* __restrict__ outf) {
  constexpr int SMEM_BYTES = (MODE == 2) ? 33792 : 32768;  // epilogue staging reuses loop LDS
  __shared__ __align__(16) char smem[SMEM_BYTES];
  ushort_t* As = (ushort_t*)smem;            // 128x32 bf16 = 8 KB
  ushort_t* Bs = (ushort_t*)(smem + 8192);   // 128x32 bf16 = 8 KB

  const int bid = blockIdx.x;
  const int xb = bid / NY;
  const int yb = bid % NY;
  const int m0 = xb * 128;
  const int n0 = yb * 128;

  const int tid = threadIdx.x;
  const int ln = tid & 63;
  const int w = tid >> 6;
  const int wr = (w >> 1) * 64, wc = (w & 1) * 64;

  const int lr = tid >> 2;
  const int kg = (tid & 3) * 8;
  const ushort_t* gA0 = A + (size_t)(m0 + lr) * D_MODEL + kg;
  const ushort_t* gA1 = gA0 + (size_t)64 * D_MODEL;
  const ushort_t* gB0 = Bt + (size_t)(n0 + lr) * D_MODEL + kg;
  const ushort_t* gB1 = gB0 + (size_t)64 * D_MODEL;

  const int wb = __builtin_amdgcn_readfirstlane(w);
  ushort_t* lA0 = As + wb * 512;
  ushort_t* lA1 = As + 2048 + wb * 512;
  ushort_t* lB0 = Bs + wb * 512;
  ushort_t* lB1 = Bs + 2048 + wb * 512;

  f32x4 acc[4][4];
  #pragma unroll
  for (int i = 0; i < 4; i++)
    #pragma unroll
    for (int j = 0; j < 4; j++) acc[i][j] = (f32x4){0.f, 0.f, 0.f, 0.f};

  const int ar = ln & 15;
  const int aq = (ln >> 4) * 8;

  for (int kt = 0; kt < D_MODEL / 32; kt++) {
    gll16(gA0, lA0); gll16(gA1, lA1);
    gll16(gB0, lB0); gll16(gB1, lB1);
    gA0 += 32; gA1 += 32; gB0 += 32; gB1 += 32;
    __syncthreads();   // drains vmcnt(0) -> LDS tiles ready
    bf16x8 a[4], b[4];
    #pragma unroll
    for (int i = 0; i < 4; i++) a[i] = *(const bf16x8*)&As[(wr + i * 16 + ar) * 32 + aq];
    #pragma unroll
    for (int j = 0; j < 4; j++) b[j] = *(const bf16x8*)&Bs[(wc + j * 16 + ar) * 32 + aq];
    #pragma unroll
    for (int i = 0; i < 4; i++)
      #pragma unroll
      for (int j = 0; j < 4; j++)
        acc[i][j] = __builtin_amdgcn_mfma_f32_16x16x32_bf16(a[i], b[j], acc[i][j], 0, 0, 0);
    __syncthreads();   // all reads done before next overwrite
  }

  // epilogue: C/D layout col=lane&15, row=(lane>>4)*4+reg  [m89-verified]
  const int colb = ln & 15;
  const int rowb = (ln >> 4) * 4;

  if (MODE == 0) {
    const int region = yb >> 3;                 // 8 y-blocks per 1024 cols
    const int nl0 = (yb & 7) * 128;
    const float* bias = region == 0 ? b0 : (region == 1 ? b1 : b2);
    ushort_t* gout    = region == 0 ? o0 : (region == 1 ? o1 : o2);
    const bool act = region < 2;
    ushort_t* Cs = (ushort_t*)smem;             // 128x128 bf16, XOR-swizzled, 32 KB
    #pragma unroll
    for (int j = 0; j < 4; j++) {
      const int col = wc + j * 16 + colb;
      const float bv_ = bias[nl0 + col];
      #pragma unroll
      for (int i = 0; i < 4; i++) {
        const int rbase = wr + i * 16 + rowb;
        #pragma unroll
        for (int r = 0; r < 4; r++) {
          float v = acc[i][j][r] + bv_;
          if (act) v = (v > 0.f) ? v + 1.f : __expf(v);   // elu(v)+1
          const int row = rbase + r;
          const int cg = col >> 3, co = col & 7;
          Cs[row * 128 + (((cg ^ (row & 15))) << 3) + co] = f2bf(v);
        }
      }
    }
    __syncthreads();
    #pragma unroll
    for (int c = 0; c < 8; c++) {
      const int idx = c * 256 + tid;
      const int row = idx >> 4, cg = idx & 15;
      short8 t = *(const short8*)&Cs[row * 128 + ((cg ^ (row & 15)) << 3)];
      *(short8*)&gout[(size_t)(m0 + row) * D_MODEL + nl0 + cg * 8] = t;
    }
  } else {
    float* Cf = (float*)smem;                   // 64x132 fp32 staging, two halves
    #pragma unroll
    for (int h = 0; h < 2; h++) {
      if (h) __syncthreads();
      if ((wr >> 6) == h) {
        #pragma unroll
        for (int j = 0; j < 4; j++) {
          const int col = wc + j * 16 + colb;
          const float bv_ = b0[n0 + col];
          #pragma unroll
          for (int i = 0; i < 4; i++) {
            const int rl = i * 16 + rowb;
            #pragma unroll
            for (int r = 0; r < 4; r++)
              Cf[(rl + r) * 132 + col] = acc[i][j][r] + bv_;
          }
        }
      }
      __syncthreads();
      #pragma unroll
      for (int c = 0; c < 8; c++) {
        const int idx = c * 256 + tid;          // 64 rows x 32 float4-groups
        const int row = idx >> 5, cg = idx & 31;
        float4 t = *(const float4*)&Cf[row * 132 + cg * 4];
        *(float4*)&outf[(size_t)(m0 + h * 64 + row) * D_MODEL + n0 + cg * 4] = t;
      }
    }
  }
}

// ---------------- kv partial: per (b,h,chunk,wave) 64x64 outer-product sum + ksum ----------------
__global__ __launch_bounds__(256) void k_kv_partial(const ushort_t* __restrict__ kmat,
                                                    const ushort_t* __restrict__ vmat,
                                                    float* __restrict__ part) {
  __shared__ __align__(16) ushort_t sbuf[4][2][2][512];  // [wave][parity][k/v][8rows*64]
  const int tid = threadIdx.x, ln = tid & 63, w = tid >> 6;
  const int wb = __builtin_amdgcn_readfirstlane(w);
  const int bh = blockIdx.y, chunk = blockIdx.x;
  const int b = bh >> 4, h = bh & 15;
  const size_t cbase = ((size_t)b * SEQ + chunk * 1024 + w * 256) * D_MODEL + h * 64;
  const ushort_t* gk = kmat + cbase + (size_t)(ln >> 3) * D_MODEL + (ln & 7) * 8;
  const ushort_t* gv = vmat + cbase + (size_t)(ln >> 3) * D_MODEL + (ln & 7) * 8;

  float acc[8][8];
  float ksum[8];
  #pragma unroll
  for (int i = 0; i < 8; i++) { ksum[i] = 0.f;
    #pragma unroll
    for (int j = 0; j < 8; j++) acc[i][j] = 0.f; }

  const int r8 = (ln >> 3) * 8, c8 = (ln & 7) * 8;
  gll16(gk, &sbuf[wb][0][0][0]);
  gll16(gv, &sbuf[wb][0][1][0]);
  gk += 8 * D_MODEL; gv += 8 * D_MODEL;

  for (int bt = 0; bt < 32; bt++) {
    const int p = bt & 1;
    if (bt < 31) {
      gll16(gk, &sbuf[wb][p ^ 1][0][0]);
      gll16(gv, &sbuf[wb][p ^ 1][1][0]);
      gk += 8 * D_MODEL; gv += 8 * D_MODEL;
      __builtin_amdgcn_s_waitcnt(0x0F72);  // vmcnt(2): current batch landed
    } else {
      __builtin_amdgcn_s_waitcnt(0x0F70);  // vmcnt(0)
    }
    #pragma unroll
    for (int s = 0; s < 8; s++) {
      short8 kk = *(const short8*)&sbuf[wb][p][0][s * 64 + r8];
      short8 vv = *(const short8*)&sbuf[wb][p][1][s * 64 + c8];
      float ka[8], va[8];
      #pragma unroll
      for (int i = 0; i < 8; i++) {
        ka[i] = __builtin_bit_cast(float, (uint32_t)(ushort_t)kk[i] << 16);
        va[i] = __builtin_bit_cast(float, (uint32_t)(ushort_t)vv[i] << 16);
      }
      #pragma unroll
      for (int i = 0; i < 8; i++) {
        ksum[i] += ka[i];
        #pragma unroll
        for (int j = 0; j < 8; j++) acc[i][j] += ka[i] * va[j];
      }
    }
  }
  float* p0 = part + ((size_t)bh * 32 + chunk * 4 + w) * 4160;
  #pragma unroll
  for (int i = 0; i < 8; i++)
    #pragma unroll
    for (int j = 0; j < 8; j++) p0[(r8 + i) * 64 + c8 + j] = acc[i][j];
  if ((ln & 7) == 0) {
    #pragma unroll
    for (int i = 0; i < 8; i++) p0[4096 + r8 + i] = ksum[i];
  }
}

// ---------------- reduce partials -> kvT bf16 [bh][65][64] (row m holds kv[.][m]; row 64 = ksum) ----------------
__global__ void k_kv_reduce(const float* __restrict__ part, ushort_t* __restrict__ kvt) {
  const int bh = blockIdx.x, tid = threadIdx.x;
  const float* p0 = part + (size_t)bh * 32 * 4160;
  for (int idx = tid; idx < 4160; idx += 256) {
    float s = 0.f;
    #pragma unroll 4
    for (int c = 0; c < 32; c++) s += p0[(size_t)c * 4160 + idx];
    ushort_t bf = f2bf(s);
    if (idx < 4096) { int d = idx >> 6, m = idx & 63; kvt[(size_t)bh * 4160 + m * 64 + d] = bf; }
    else            { kvt[(size_t)bh * 4160 + 4096 + (idx - 4096)] = bf; }
  }
}

// ---------------- attn: out = (q @ kv) / max(q . ksum, eps), bf16 out ----------------
__global__ __launch_bounds__(256) void k_attn(const ushort_t* __restrict__ qmat,
                                              const ushort_t* __restrict__ kvt,
                                              ushort_t* __restrict__ attn) {
  __shared__ __align__(16) ushort_t kvs[65 * 80];     // kvT rows stride 80
  __shared__ __align__(16) ushort_t qs[4][64 * 80];   // per-wave q tile, stride 80
  const int tid = threadIdx.x, ln = tid & 63, w = tid >> 6;
  const int bh = blockIdx.y, b = bh >> 4, h = bh & 15;

  for (int idx = tid; idx < 4160; idx += 256) {
    int m = idx >> 6, d = idx & 63;
    kvs[m * 80 + d] = kvt[(size_t)bh * 4160 + idx];
  }
  const size_t s0 = (size_t)b * SEQ + blockIdx.x * 256 + w * 64;
  #pragma unroll
  for (int c = 0; c < 8; c++) {
    int f = c * 64 + ln;
    int row = f >> 3, dg = (f & 7) * 8;
    short8 t = *(const short8*)&qmat[(s0 + row) * D_MODEL + h * 64 + dg];
    *(short8*)&qs[w][row * 80 + dg] = t;
  }
  __syncthreads();

  const int ar = ln & 15, aq = (ln >> 4) * 8;
  f32x4 acc[4][4], nacc[4];
  #pragma unroll
  for (int i = 0; i < 4; i++) { nacc[i] = (f32x4){0.f, 0.f, 0.f, 0.f};
    #pragma unroll
    for (int j = 0; j < 4; j++) acc[i][j] = (f32x4){0.f, 0.f, 0.f, 0.f}; }

  #pragma unroll
  for (int kk = 0; kk < 2; kk++) {
    const int ko = kk * 32 + aq;
    bf16x8 a[4], bb[4], bn;
    #pragma unroll
    for (int i = 0; i < 4; i++) a[i] = *(const bf16x8*)&qs[w][(i * 16 + ar) * 80 + ko];
    #pragma unroll
    for (int j = 0; j < 4; j++) bb[j] = *(const bf16x8*)&kvs[(j * 16 + ar) * 80 + ko];
    bn = *(const bf16x8*)&kvs[64 * 80 + ko];
    #pragma unroll
    for (int i = 0; i < 4; i++) {
      #pragma unroll
      for (int j = 0; j < 4; j++)
        acc[i][j] = __builtin_amdgcn_mfma_f32_16x16x32_bf16(a[i], bb[j], acc[i][j], 0, 0, 0);
      nacc[i] = __builtin_amdgcn_mfma_f32_16x16x32_bf16(a[i], bn, nacc[i], 0, 0, 0);
    }
  }

  const int colb = ln & 15, rowb = (ln >> 4) * 4;
  #pragma unroll
  for (int i = 0; i < 4; i++) {
    #pragma unroll
    for (int r = 0; r < 4; r++) {
      const int row = i * 16 + rowb + r;
      float nm = fmaxf(nacc[i][r], 1e-6f);
      float inv = 1.0f / nm;
      const size_t grow = s0 + row;
      #pragma unroll
      for (int j = 0; j < 4; j++) {
        float v = acc[i][j][r] * inv;
        attn[grow * D_MODEL + h * 64 + j * 16 + colb] = f2bf(v);
      }
    }
  }
}

extern "C" void kernel_launch(void* const* d_in, const int* in_sizes, int n_in,
                              void* d_out, int out_size, void* d_ws, size_t ws_size,
                              hipStream_t stream) {
  const float* x  = (const float*)d_in[0];
  const float* Wq = (const float*)d_in[1];
  const float* bq = (const float*)d_in[2];
  const float* Wk = (const float*)d_in[3];
  const float* bk = (const float*)d_in[4];
  const float* Wv = (const float*)d_in[5];
  const float* bv = (const float*)d_in[6];
  const float* Wo = (const float*)d_in[7];
  const float* bo = (const float*)d_in[8];
  float* out = (float*)d_out;

  const int M = in_sizes[0] / D_MODEL;       // 32768
  const int B = M / SEQ;                     // 4
  const int BH = B * 16;                     // 64

  char* ws = (char*)d_ws;
  size_t off = 0;
  auto alloc = [&](size_t bytes) { char* p = ws + off; off += (bytes + 255) & ~(size_t)255; return p; };
  const size_t mb = (size_t)M * D_MODEL * 2;               // 64 MB per bf16 matrix
  ushort_t* xb    = (ushort_t*)alloc(mb);
  ushort_t* qb    = (ushort_t*)alloc(mb);
  ushort_t* kb    = (ushort_t*)alloc(mb);
  ushort_t* vb    = (ushort_t*)alloc(mb);
  ushort_t* attnb = (ushort_t*)alloc(mb);
  ushort_t* wqkvt = (ushort_t*)alloc((size_t)3 * D_MODEL * D_MODEL * 2);
  ushort_t* wot   = (ushort_t*)alloc((size_t)D_MODEL * D_MODEL * 2);
  ushort_t* kvt   = (ushort_t*)alloc((size_t)BH * 4160 * 2);
  float*    part  = (float*)   alloc((size_t)BH * 32 * 4160 * 4);
  (void)ws_size; (void)n_in; (void)out_size;

  const int n = M * D_MODEL;
  k_convert_x<<<n / (256 * 8), 256, 0, stream>>>(x, xb, n);
  k_transpose_w<<<dim3(16, 16, 4), 256, 0, stream>>>(Wq, Wk, Wv, Wo, wqkvt, wot);

  // Fused QKV: N = 3072, 1D grid decoded N-fastest for A-tile L2 reuse
  k_gemm<0, 24><<<(M / 128) * 24, 256, 0, stream>>>(xb, wqkvt, bq, bk, bv, qb, kb, vb, nullptr);

  k_kv_partial<<<dim3(8, BH), 256, 0, stream>>>(kb, vb, part);
  k_kv_reduce<<<BH, 256, 0, stream>>>(part, kvt);
  k_attn<<<dim3(SEQ / 256, BH), 256, 0, stream>>>(qb, kvt, attnb);

  // Output projection: fp32 out
  k_gemm<2, 8><<<(M / 128) * 8, 256, 0, stream>>>(attnb, wot, bo, nullptr, nullptr, nullptr, nullptr, nullptr, out);
}